// Round 2
// baseline (995.657 us; speedup 1.0000x reference)
//
#include <hip/hip_runtime.h>

// 2-layer GRU (B=1024, T=512, F=128, H=64) + ReLU + FC(64->18), fp32 in/out.
//
// R5: kill the per-tick vmcnt(0) drain. __syncthreads() emits
// "s_waitcnt vmcnt(0) lgkmcnt(0)" before s_barrier, which forced every
// tick to synchronously retire the x-prefetch HBM loads (~900 cy exposed;
// state=268MB > L3). Replace the tick barrier with
//   s_waitcnt lgkmcnt(0)   (LDS write visibility only)
//   s_barrier              (raw builtin)
// so prefetch loads float across barriers (counted vmcnt at the convert
// only). Prefetch deepened to distance-3 via double f32 staging buffers
// (GA/GB, parity-static indexing) -> ~2 ticks of latency cover.
// MFMA chains rebalanced: all 2-deep (gx-lo, gx-hi, hh) + f32x4 adds.
//
//   waves 0-3 (A): h0(t) = GRUcell(x(t)@Wih0.T (in-reg gx), h0(t-1)); 18 MFMA.
//   waves 4-7 (B): h1(t-1) = GRUcell(h0(t-1), h1(t-2)); 12 MFMA.
// One raw barrier per tick. setprio(1) around MFMA clusters.

#define Tn 512
#define Fn 128
#define Hn 64
#define An 18
// padded h row stride (halves): 72 -> 144B rows
#define HS 72

typedef _Float16 half8 __attribute__((ext_vector_type(8)));
typedef float f32x4 __attribute__((ext_vector_type(4)));

#define MFMA(a, b, c) __builtin_amdgcn_mfma_f32_16x16x32_f16((a), (b), (c), 0, 0, 0)

// Clamp-free: exp2(+-inf) saturates, rcp(inf)->0.
static __device__ __forceinline__ float sigm(float x) {
    return __builtin_amdgcn_rcpf(1.0f + __builtin_amdgcn_exp2f(-1.4426950408889634f * x));
}
static __device__ __forceinline__ float tanh_f(float x) {
    return 2.0f * __builtin_amdgcn_rcpf(1.0f + __builtin_amdgcn_exp2f(-2.8853900817779268f * x)) - 1.0f;
}

// x staging: load one timestep's f32 row-fragment into an 8x f32x4 buffer
#define LOADX(Gbuf, tt) do {                                              \
    const float* _p = srow + (size_t)(tt) * Fn;                           \
    _Pragma("unroll")                                                     \
    for (int _ks = 0; _ks < 4; ++_ks) {                                   \
        Gbuf[2 * _ks]     = *(const f32x4*)(_p + _ks * 32 + q * 8);       \
        Gbuf[2 * _ks + 1] = *(const f32x4*)(_p + _ks * 32 + q * 8 + 4);   \
    }                                                                     \
} while (0)

// convert a staged f32 buffer into the 4 half8 A-fragments
#define CVTX(Gbuf) do {                                                   \
    _Pragma("unroll")                                                     \
    for (int _ks = 0; _ks < 4; ++_ks)                                     \
        _Pragma("unroll")                                                 \
        for (int _i = 0; _i < 4; ++_i) {                                  \
            xf[_ks][_i]     = (_Float16)Gbuf[2 * _ks][_i];                \
            xf[_ks][4 + _i] = (_Float16)Gbuf[2 * _ks + 1][_i];            \
        }                                                                 \
} while (0)

__global__ __launch_bounds__(512, 2) void gru_fused(
    const float* __restrict__ state,
    const float* __restrict__ Wih0, const float* __restrict__ Whh0,
    const float* __restrict__ bih0, const float* __restrict__ bhh0,
    const float* __restrict__ Wih1, const float* __restrict__ Whh1,
    const float* __restrict__ bih1, const float* __restrict__ bhh1,
    const float* __restrict__ fcw, const float* __restrict__ fcb,
    float* __restrict__ out)
{
    const int tid  = threadIdx.x;
    const int wv8  = tid >> 6;
    const int lane = tid & 63, c = lane & 15, q = lane >> 4;
    const int wv   = wv8 & 3;
    const int r0   = blockIdx.x * 16;
    const int gc   = wv * 16 + c;
    const int roleB = (wv8 >= 4);

    __shared__ __align__(16) _Float16 h0buf[2][16 * HS];        // 4.5 KiB
    __shared__ __align__(16) _Float16 h1buf[2][16 * HS];        // 4.5 KiB
    __shared__ float fbuf[16 * 64];                             // 4 KiB

    for (int i = tid; i < 2 * 16 * HS; i += 512) {
        (&h0buf[0][0])[i] = (_Float16)0.0f;
        (&h1buf[0][0])[i] = (_Float16)0.0f;
    }

    // Weight fragments (B-operand layout: lane(c,q) holds W[n=g][k=ks*32+q*8+j]):
    //  A: W[gsel*4+ks]   = Wih0 (k=128, 4 ksteps)
    //     W[12+gsel*2+ks]= Whh0 (k=64, 2 ksteps)
    //  B: W[gsel*2+ks]   = Wih1 ; W[6+gsel*2+ks] = Whh1
    half8 W[18];
    f32x4 bias0, bias1, bias2, bias3;
    f32x4 GA[8], GB[8];
    half8 xf[4];
    f32x4 hreg = {0.f, 0.f, 0.f, 0.f};
    const float* srow = state + (size_t)(r0 + c) * (Tn * Fn);

    if (!roleB) {
#pragma unroll
        for (int gsel = 0; gsel < 3; ++gsel) {
            const int g = gsel * 64 + gc;
#pragma unroll
            for (int ks = 0; ks < 4; ++ks) {
                const float* p = Wih0 + g * Fn + ks * 32 + q * 8;
#pragma unroll
                for (int j = 0; j < 8; ++j) W[gsel * 4 + ks][j] = (_Float16)p[j];
            }
#pragma unroll
            for (int ks = 0; ks < 2; ++ks) {
                const float* p = Whh0 + g * Hn + ks * 32 + q * 8;
#pragma unroll
                for (int j = 0; j < 8; ++j) W[12 + gsel * 2 + ks][j] = (_Float16)p[j];
            }
        }
        {
            const float b0 = bih0[gc] + bhh0[gc];
            const float b1 = bih0[64 + gc] + bhh0[64 + gc];
            const float b2 = bih0[128 + gc];
            const float b3 = bhh0[128 + gc];
            bias0 = (f32x4){b0, b0, b0, b0};
            bias1 = (f32x4){b1, b1, b1, b1};
            bias2 = (f32x4){b2, b2, b2, b2};
            bias3 = (f32x4){b3, b3, b3, b3};
        }
        // prologue: x(0)->GA, x(1)->GB, convert x(0)->xf, then x(2)->GA.
        LOADX(GA, 0);
        LOADX(GB, 1);
        CVTX(GA);
        LOADX(GA, 2);
    } else {
#pragma unroll
        for (int gsel = 0; gsel < 3; ++gsel) {
            const int g = gsel * 64 + gc;
#pragma unroll
            for (int ks = 0; ks < 2; ++ks) {
                const float* pa = Wih1 + g * Hn + ks * 32 + q * 8;
                const float* pb = Whh1 + g * Hn + ks * 32 + q * 8;
#pragma unroll
                for (int j = 0; j < 8; ++j) {
                    W[gsel * 2 + ks][j]     = (_Float16)pa[j];
                    W[6 + gsel * 2 + ks][j] = (_Float16)pb[j];
                }
            }
        }
        const float br_ = bih1[gc] + bhh1[gc];
        const float bz_ = bih1[64 + gc] + bhh1[64 + gc];
        const float bxn = bih1[128 + gc];
        const float bhn = bhh1[128 + gc];
        bias0 = (f32x4){br_, br_, br_, br_};
        bias1 = (f32x4){bz_, bz_, bz_, bz_};
        bias2 = (f32x4){bxn, bxn, bxn, bxn};
        bias3 = (f32x4){bhn, bhn, bhn, bhn};
    }

    const int ardr = c * HS + q * 8;        // A-frag read base (+32 for kstep 1)
    const int wrow = (q * 4) * HS + gc;     // C-layout write base (+i*HS)
    const f32x4 z4 = {0.f, 0.f, 0.f, 0.f};

    // Tick t: A makes h0(t) (t<Tn); B makes h1(t-1) (t>=1)
    for (int t = 0; t <= Tn; ++t) {
        // LDS-visibility-only barrier: drain DS ops, leave global loads in
        // flight (counted vmcnt at the convert is the only vmem wait).
        asm volatile("s_waitcnt lgkmcnt(0)" ::: "memory");
        __builtin_amdgcn_s_barrier();
        asm volatile("" ::: "memory");
        const int pr = (t & 1) ^ 1, pw = t & 1;
        if (!roleB) {
            if (t < Tn) {
                const half8 hf0 = *(const half8*)&h0buf[pr][ardr];
                const half8 hf1 = *(const half8*)&h0buf[pr][ardr + 32];
                __builtin_amdgcn_s_setprio(1);
                // gx chains (pure register, issue immediately at tick start)
                f32x4 ar = MFMA(xf[0], W[0], bias0);  ar = MFMA(xf[1], W[1], ar);
                f32x4 az = MFMA(xf[0], W[4], bias1);  az = MFMA(xf[1], W[5], az);
                f32x4 an = MFMA(xf[0], W[8], bias2);  an = MFMA(xf[1], W[9], an);
                f32x4 br = MFMA(xf[2], W[2], z4);     br = MFMA(xf[3], W[3], br);
                f32x4 bz = MFMA(xf[2], W[6], z4);     bz = MFMA(xf[3], W[7], bz);
                f32x4 bn = MFMA(xf[2], W[10], z4);    bn = MFMA(xf[3], W[11], bn);
                // hh chains (wait on LDS h0(t-1); independent 2-deep chains)
                f32x4 hr = MFMA(hf0, W[12], z4);      hr = MFMA(hf1, W[13], hr);
                f32x4 hz = MFMA(hf0, W[14], z4);      hz = MFMA(hf1, W[15], hz);
                f32x4 hn = MFMA(hf0, W[16], bias3);   hn = MFMA(hf1, W[17], hn);
                __builtin_amdgcn_s_setprio(0);
                // next-x convert (2-tick-old loads) + distance-3 prefetch
                if (t < Tn - 1) {
                    const int tnx = (t + 3 < Tn) ? (t + 3) : (Tn - 1);
                    if ((t & 1) == 0) { CVTX(GB); LOADX(GB, tnx); }
                    else              { CVTX(GA); LOADX(GA, tnx); }
                }
                const f32x4 accr  = (ar + br) + hr;
                const f32x4 accz  = (az + bz) + hz;
                const f32x4 accxn = an + bn;
#pragma unroll
                for (int i = 0; i < 4; ++i) {
                    const float rg = sigm(accr[i]);
                    const float zg = sigm(accz[i]);
                    const float ng = tanh_f(accxn[i] + rg * hn[i]);
                    hreg[i] = ng + zg * (hreg[i] - ng);
                }
#pragma unroll
                for (int i = 0; i < 4; ++i) h0buf[pw][wrow + i * HS] = (_Float16)hreg[i];
            }
        } else {
            if (t >= 1) {
                const half8 xf0 = *(const half8*)&h0buf[pr][ardr];
                const half8 xf1 = *(const half8*)&h0buf[pr][ardr + 32];
                const half8 hf0 = *(const half8*)&h1buf[pw][ardr];
                const half8 hf1 = *(const half8*)&h1buf[pw][ardr + 32];
                __builtin_amdgcn_s_setprio(1);
                f32x4 xr = MFMA(xf0, W[0], bias0);  xr = MFMA(xf1, W[1], xr);
                f32x4 xz = MFMA(xf0, W[2], bias1);  xz = MFMA(xf1, W[3], xz);
                f32x4 xn = MFMA(xf0, W[4], bias2);  xn = MFMA(xf1, W[5], xn);
                f32x4 hr = MFMA(hf0, W[6], z4);     hr = MFMA(hf1, W[7], hr);
                f32x4 hz = MFMA(hf0, W[8], z4);     hz = MFMA(hf1, W[9], hz);
                f32x4 hn = MFMA(hf0, W[10], bias3); hn = MFMA(hf1, W[11], hn);
                __builtin_amdgcn_s_setprio(0);
                const f32x4 accr = xr + hr;
                const f32x4 accz = xz + hz;
#pragma unroll
                for (int i = 0; i < 4; ++i) {
                    const float rg = sigm(accr[i]);
                    const float zg = sigm(accz[i]);
                    const float ng = tanh_f(xn[i] + rg * hn[i]);
                    hreg[i] = ng + zg * (hreg[i] - ng);
                }
#pragma unroll
                for (int i = 0; i < 4; ++i) h1buf[pr][wrow + i * HS] = (_Float16)hreg[i];
            }
        }
    }

    // epilogue: relu(h1_final) @ fc3_w.T + fc3_b   (role B holds h1(Tn-1))
    if (roleB) {
#pragma unroll
        for (int i = 0; i < 4; ++i) fbuf[(q * 4 + i) * 64 + gc] = fmaxf(hreg[i], 0.0f);
    }
    __syncthreads();
    for (int idx = tid; idx < 16 * An; idx += 512) {
        const int row = idx / An, a = idx - row * An;
        float acc = fcb[a];
#pragma unroll 16
        for (int k = 0; k < Hn; ++k) acc += fbuf[row * 64 + k] * fcw[a * Hn + k];
        out[(size_t)(r0 + row) * An + a] = acc;
    }
}

extern "C" void kernel_launch(void* const* d_in, const int* in_sizes, int n_in,
                              void* d_out, int out_size, void* d_ws, size_t ws_size,
                              hipStream_t stream) {
    const float* state = (const float*)d_in[0];
    const float* Wih0  = (const float*)d_in[1];
    const float* Whh0  = (const float*)d_in[2];
    const float* bih0  = (const float*)d_in[3];
    const float* bhh0  = (const float*)d_in[4];
    const float* Wih1  = (const float*)d_in[5];
    const float* Whh1  = (const float*)d_in[6];
    const float* bih1  = (const float*)d_in[7];
    const float* bhh1  = (const float*)d_in[8];
    const float* fcw   = (const float*)d_in[9];
    const float* fcb   = (const float*)d_in[10];
    float* out = (float*)d_out;

    gru_fused<<<64, 512, 0, stream>>>(state, Wih0, Whh0, bih0, bhh0,
                                      Wih1, Whh1, bih1, bhh1, fcw, fcb, out);
}

// Round 5
// 758.543 us; speedup vs baseline: 1.3126x; 1.3126x over previous
//
#include <hip/hip_runtime.h>

// 2-layer GRU (B=1024, T=512, F=128, H=64) + ReLU + FC(64->18), fp32 in/out.
//
// R8 = R6/R7 with the cvt_pkrtz type fixed (__fp16 vector, the builtin's
// native return type). R6's bench was an infra failure; R7 failed compile.
// Experiment unchanged: R3 skeleton (best measured: 483us) + one structural
// change: the per-tick __syncthreads() (emits s_waitcnt vmcnt(0) lgkmcnt(0))
// replaced by {s_waitcnt lgkmcnt(0); s_barrier} so x-prefetch global loads
// are never drained at the barrier. Plus two P-only micro-opts (P is off
// the recurrence critical path): v_cvt_pkrtz packing for the f32->f16 x
// convert, and 2+2 MFMA chain split.
//
// 64 blocks x 768 threads (12 waves, 3/SIMD), one block per 16-row tile:
//   waves 0-3  (P):  gx(t+1) = x(t+1) @ W_ih0.T + bias -> 2-slot LDS ring,
//                    f32 C-layout. Distance-1 HBM prefetch of x.
//   waves 4-7  (L0): h0(t) = GRUcell(gx(t), h0(t-1))     [6 MFMA + nonlin]
//   waves 8-11 (L1): h1(t-1) = GRUcell(h0(t-1), h1(t-2)) [12 MFMA + nonlin]
// One barrier per tick.

#define Tn 512
#define Fn 128
#define Hn 64
#define An 18
// padded h row stride (halves): 72 -> 144B rows
#define HS 72

typedef _Float16 half8 __attribute__((ext_vector_type(8)));
typedef __fp16 fp16x2 __attribute__((ext_vector_type(2)));   // cvt_pkrtz native type
typedef float f32x4 __attribute__((ext_vector_type(4)));

#define MFMA(a, b, c) __builtin_amdgcn_mfma_f32_16x16x32_f16((a), (b), (c), 0, 0, 0)

// Clamp-free: exp2(+-inf) saturates, rcp(inf)->0.
static __device__ __forceinline__ float sigm(float x) {
    return __builtin_amdgcn_rcpf(1.0f + __builtin_amdgcn_exp2f(-1.4426950408889634f * x));
}
static __device__ __forceinline__ float tanh_f(float x) {
    return 2.0f * __builtin_amdgcn_rcpf(1.0f + __builtin_amdgcn_exp2f(-2.8853900817779268f * x)) - 1.0f;
}

// pack two f32x4 into one half8 A-fragment via v_cvt_pkrtz (4 insts vs ~12)
static __device__ __forceinline__ half8 pack8(const f32x4 a, const f32x4 b) {
    union { half8 h8; fp16x2 h2[4]; } u;
    u.h2[0] = __builtin_amdgcn_cvt_pkrtz(a[0], a[1]);
    u.h2[1] = __builtin_amdgcn_cvt_pkrtz(a[2], a[3]);
    u.h2[2] = __builtin_amdgcn_cvt_pkrtz(b[0], b[1]);
    u.h2[3] = __builtin_amdgcn_cvt_pkrtz(b[2], b[3]);
    return u.h8;
}

__global__ __launch_bounds__(768) void gru_fused(
    const float* __restrict__ state,
    const float* __restrict__ Wih0, const float* __restrict__ Whh0,
    const float* __restrict__ bih0, const float* __restrict__ bhh0,
    const float* __restrict__ Wih1, const float* __restrict__ Whh1,
    const float* __restrict__ bih1, const float* __restrict__ bhh1,
    const float* __restrict__ fcw, const float* __restrict__ fcb,
    float* __restrict__ out)
{
    const int tid  = threadIdx.x;
    const int wv12 = tid >> 6;
    const int lane = tid & 63, c = lane & 15, q = lane >> 4;
    const int wv   = wv12 & 3;
    const int r0   = blockIdx.x * 16;
    const int gc   = wv * 16 + c;
    const int role = (wv12 < 4) ? 0 : (wv12 < 8 ? 1 : 2);

    __shared__ __align__(16) float    gxring[2][4][3][64][4];   // 24 KiB
    __shared__ __align__(16) _Float16 h0buf[2][16 * HS];        // 4.5 KiB
    __shared__ __align__(16) _Float16 h1buf[2][16 * HS];        // 4.5 KiB
    __shared__ float fbuf[16 * 64];                             // 4 KiB

    for (int i = tid; i < 2 * 16 * HS; i += 768) {
        (&h0buf[0][0])[i] = (_Float16)0.0f;
        (&h1buf[0][0])[i] = (_Float16)0.0f;
    }

    // Unioned weight fragments:
    //  P : W[gsel*4+ks] = Wih0 (k=128, 4 ksteps)
    //  L0: W[gsel*2+ks] = Whh0 (k=64, 2 ksteps)
    //  L1: W[gsel*2+ks] = Wih1 ; W[6+gsel*2+ks] = Whh1
    half8 W[12];
    f32x4 bias0, bias1, bias2, bias3;
    f32x4 xf32[8];
    f32x4 hreg = {0.f, 0.f, 0.f, 0.f};
    const float* srow = state + (size_t)(r0 + c) * (Tn * Fn);

    if (role == 0) {
#pragma unroll
        for (int gsel = 0; gsel < 3; ++gsel) {
            const int g = gsel * 64 + gc;
#pragma unroll
            for (int ks = 0; ks < 4; ++ks) {
                const float* p = Wih0 + g * Fn + ks * 32 + q * 8;
#pragma unroll
                for (int j = 0; j < 8; ++j) W[gsel * 4 + ks][j] = (_Float16)p[j];
            }
        }
        {
            const float b0 = bih0[gc] + bhh0[gc];
            const float b1 = bih0[64 + gc] + bhh0[64 + gc];
            const float b2 = bih0[128 + gc];
            bias0 = (f32x4){b0, b0, b0, b0};
            bias1 = (f32x4){b1, b1, b1, b1};
            bias2 = (f32x4){b2, b2, b2, b2};
        }
        // -------- prologue: gx(0) -> ring slot 0; preload x(1) --------
#pragma unroll
        for (int ks = 0; ks < 4; ++ks) {
            xf32[2 * ks]     = *(const f32x4*)(srow + ks * 32 + q * 8);
            xf32[2 * ks + 1] = *(const f32x4*)(srow + ks * 32 + q * 8 + 4);
        }
        half8 xf[4];
#pragma unroll
        for (int ks = 0; ks < 4; ++ks) xf[ks] = pack8(xf32[2 * ks], xf32[2 * ks + 1]);
        f32x4 a0 = bias0, a1 = bias1, a2 = bias2;
#pragma unroll
        for (int ks = 0; ks < 4; ++ks) {
            a0 = MFMA(xf[ks], W[ks], a0);
            a1 = MFMA(xf[ks], W[4 + ks], a1);
            a2 = MFMA(xf[ks], W[8 + ks], a2);
        }
        *(f32x4*)&gxring[0][wv][0][lane][0] = a0;
        *(f32x4*)&gxring[0][wv][1][lane][0] = a1;
        *(f32x4*)&gxring[0][wv][2][lane][0] = a2;
#pragma unroll
        for (int ks = 0; ks < 4; ++ks) {
            xf32[2 * ks]     = *(const f32x4*)(srow + Fn + ks * 32 + q * 8);
            xf32[2 * ks + 1] = *(const f32x4*)(srow + Fn + ks * 32 + q * 8 + 4);
        }
    } else if (role == 1) {
#pragma unroll
        for (int gsel = 0; gsel < 3; ++gsel) {
            const int g = gsel * 64 + gc;
#pragma unroll
            for (int ks = 0; ks < 2; ++ks) {
                const float* p = Whh0 + g * Hn + ks * 32 + q * 8;
#pragma unroll
                for (int j = 0; j < 8; ++j) W[gsel * 2 + ks][j] = (_Float16)p[j];
            }
        }
        const float bhn = bhh0[128 + gc];
        bias3 = (f32x4){bhn, bhn, bhn, bhn};
    } else {
#pragma unroll
        for (int gsel = 0; gsel < 3; ++gsel) {
            const int g = gsel * 64 + gc;
#pragma unroll
            for (int ks = 0; ks < 2; ++ks) {
                const float* pa = Wih1 + g * Hn + ks * 32 + q * 8;
                const float* pb = Whh1 + g * Hn + ks * 32 + q * 8;
#pragma unroll
                for (int j = 0; j < 8; ++j) {
                    W[gsel * 2 + ks][j]     = (_Float16)pa[j];
                    W[6 + gsel * 2 + ks][j] = (_Float16)pb[j];
                }
            }
        }
        const float br = bih1[gc] + bhh1[gc];
        const float bz = bih1[64 + gc] + bhh1[64 + gc];
        const float bxn = bih1[128 + gc];
        const float bhn = bhh1[128 + gc];
        bias0 = (f32x4){br, br, br, br};
        bias1 = (f32x4){bz, bz, bz, bz};
        bias2 = (f32x4){bxn, bxn, bxn, bxn};
        bias3 = (f32x4){bhn, bhn, bhn, bhn};
    }

    const int ardr = c * HS + q * 8;        // A-frag read base (+ks*32)
    const int wrow = (q * 4) * HS + gc;     // C-layout write base (+i*HS)
    const f32x4 z4 = {0.f, 0.f, 0.f, 0.f};

    // Tick t: P makes gx(t+1) (t<Tn-1); L0 makes h0(t) (t<Tn); L1 makes h1(t-1) (t>=1)
    for (int t = 0; t <= Tn; ++t) {
        // LDS-visibility-only barrier: flush DS ops, leave the x-prefetch
        // global loads in flight (no vmcnt(0) drain; the only vmem wait is
        // the compiler-counted one before the convert that consumes them).
        asm volatile("s_waitcnt lgkmcnt(0)" ::: "memory");
        __builtin_amdgcn_s_barrier();
        asm volatile("" ::: "memory");
        const int pr = (t & 1) ^ 1, pw = t & 1;
        if (role == 0) {
            if (t < Tn - 1) {
                half8 xf[4];
#pragma unroll
                for (int ks = 0; ks < 4; ++ks) xf[ks] = pack8(xf32[2 * ks], xf32[2 * ks + 1]);
                const int tnx = (t + 2 < Tn) ? (t + 2) : (Tn - 1);
#pragma unroll
                for (int ks = 0; ks < 4; ++ks) {
                    xf32[2 * ks]     = *(const f32x4*)(srow + (size_t)tnx * Fn + ks * 32 + q * 8);
                    xf32[2 * ks + 1] = *(const f32x4*)(srow + (size_t)tnx * Fn + ks * 32 + q * 8 + 4);
                }
                // 2+2 chains per gate (shorter dependent-MFMA latency)
                f32x4 a0 = MFMA(xf[0], W[0], bias0);  a0 = MFMA(xf[1], W[1], a0);
                f32x4 c0 = MFMA(xf[2], W[2], z4);     c0 = MFMA(xf[3], W[3], c0);
                f32x4 a1 = MFMA(xf[0], W[4], bias1);  a1 = MFMA(xf[1], W[5], a1);
                f32x4 c1 = MFMA(xf[2], W[6], z4);     c1 = MFMA(xf[3], W[7], c1);
                f32x4 a2 = MFMA(xf[0], W[8], bias2);  a2 = MFMA(xf[1], W[9], a2);
                f32x4 c2 = MFMA(xf[2], W[10], z4);    c2 = MFMA(xf[3], W[11], c2);
                const int slot = (t + 1) & 1;
                *(f32x4*)&gxring[slot][wv][0][lane][0] = a0 + c0;
                *(f32x4*)&gxring[slot][wv][1][lane][0] = a1 + c1;
                *(f32x4*)&gxring[slot][wv][2][lane][0] = a2 + c2;
            }
        } else if (role == 1) {
            if (t < Tn) {
                f32x4 accr  = *(const f32x4*)&gxring[t & 1][wv][0][lane][0];
                f32x4 accz  = *(const f32x4*)&gxring[t & 1][wv][1][lane][0];
                f32x4 accxn = *(const f32x4*)&gxring[t & 1][wv][2][lane][0];
                const half8 hf0 = *(const half8*)&h0buf[pr][ardr];
                const half8 hf1 = *(const half8*)&h0buf[pr][ardr + 32];
                accr = MFMA(hf0, W[0], accr);
                accr = MFMA(hf1, W[1], accr);
                accz = MFMA(hf0, W[2], accz);
                accz = MFMA(hf1, W[3], accz);
                f32x4 acchn = MFMA(hf0, W[4], bias3);
                acchn = MFMA(hf1, W[5], acchn);
#pragma unroll
                for (int i = 0; i < 4; ++i) {
                    const float rg = sigm(accr[i]);
                    const float zg = sigm(accz[i]);
                    const float ng = tanh_f(accxn[i] + rg * acchn[i]);
                    hreg[i] = ng + zg * (hreg[i] - ng);
                }
#pragma unroll
                for (int i = 0; i < 4; ++i) h0buf[pw][wrow + i * HS] = (_Float16)hreg[i];
            }
        } else {
            if (t >= 1) {
                const half8 xf0 = *(const half8*)&h0buf[pr][ardr];
                const half8 xf1 = *(const half8*)&h0buf[pr][ardr + 32];
                const half8 hf0 = *(const half8*)&h1buf[pw][ardr];
                const half8 hf1 = *(const half8*)&h1buf[pw][ardr + 32];
                f32x4 accr = MFMA(xf0, W[0], bias0);
                accr = MFMA(xf1, W[1], accr);
                f32x4 accz = MFMA(xf0, W[2], bias1);
                accz = MFMA(xf1, W[3], accz);
                f32x4 accxn = MFMA(xf0, W[4], bias2);
                accxn = MFMA(xf1, W[5], accxn);
                accr = MFMA(hf0, W[6], accr);
                accr = MFMA(hf1, W[7], accr);
                accz = MFMA(hf0, W[8], accz);
                accz = MFMA(hf1, W[9], accz);
                f32x4 acchn = MFMA(hf0, W[10], bias3);
                acchn = MFMA(hf1, W[11], acchn);
#pragma unroll
                for (int i = 0; i < 4; ++i) {
                    const float rg = sigm(accr[i]);
                    const float zg = sigm(accz[i]);
                    const float ng = tanh_f(accxn[i] + rg * acchn[i]);
                    hreg[i] = ng + zg * (hreg[i] - ng);
                }
#pragma unroll
                for (int i = 0; i < 4; ++i) h1buf[pr][wrow + i * HS] = (_Float16)hreg[i];
            }
        }
    }

    // epilogue: relu(h1_final) @ fc3_w.T + fc3_b
    if (role == 2) {
#pragma unroll
        for (int i = 0; i < 4; ++i) fbuf[(q * 4 + i) * 64 + gc] = fmaxf(hreg[i], 0.0f);
    }
    __syncthreads();
    for (int idx = tid; idx < 16 * An; idx += 768) {
        const int row = idx / An, a = idx - row * An;
        float acc = fcb[a];
#pragma unroll 16
        for (int k = 0; k < Hn; ++k) acc += fbuf[row * 64 + k] * fcw[a * Hn + k];
        out[(size_t)(r0 + row) * An + a] = acc;
    }
}

extern "C" void kernel_launch(void* const* d_in, const int* in_sizes, int n_in,
                              void* d_out, int out_size, void* d_ws, size_t ws_size,
                              hipStream_t stream) {
    const float* state = (const float*)d_in[0];
    const float* Wih0  = (const float*)d_in[1];
    const float* Whh0  = (const float*)d_in[2];
    const float* bih0  = (const float*)d_in[3];
    const float* bhh0  = (const float*)d_in[4];
    const float* Wih1  = (const float*)d_in[5];
    const float* Whh1  = (const float*)d_in[6];
    const float* bih1  = (const float*)d_in[7];
    const float* bhh1  = (const float*)d_in[8];
    const float* fcw   = (const float*)d_in[9];
    const float* fcb   = (const float*)d_in[10];
    float* out = (float*)d_out;

    gru_fused<<<64, 768, 0, stream>>>(state, Wih0, Whh0, bih0, bhh0,
                                      Wih1, Whh1, bih1, bhh1, fcw, fcb, out);
}

// Round 6
// 741.684 us; speedup vs baseline: 1.3424x; 1.0227x over previous
//
#include <hip/hip_runtime.h>

// 2-layer GRU (B=1024, T=512, F=128, H=64) + ReLU + FC(64->18), fp32 in/out.
//
// R9 = R3 skeleton (best measured: 483us; __syncthreads per tick) with an
// instruction/DS-op diet based on the issue-port model (VALUBusy 40% per
// active CU = ~900cy/SIMD/tick of issue; LDS pipe ~770cy/CU/tick):
//  1. MFMA operand swap: W is the A operand, x/h the B operand. A/B frag
//     lane maps are identical for 16x16x32, so W/x/h loads are UNCHANGED;
//     only the C output transposes to (channel, batch). Result: h-state
//     writes become ONE ds_write_b64 of 4 consecutive channels per thread
//     (was 4x strided ds_write_b16). Per-CU DS ops 80 -> 56.
//  2. Gate pre-scaling: weights+biases scaled by -1.4427 (r,z) / -2.8854
//     (n) at fragment-load time -> sigm/tanh input muls deleted
//     (12 VALU per L-wave per tick).
//  3. Per-channel f32x4 biases; f32x4 epilogue write; scalar RNE x-cvt
//     (R8's RTZ pkrtz doubled absmax - dropped).
//
// 64 blocks x 768 threads (12 waves, 3/SIMD), one block per 16-row tile:
//   waves 0-3  (P):  gx(t+1) = Wih0~ @ x(t+1) + b~ -> 2-slot LDS ring,
//                    f32 C-layout (ch,batch). Distance-1 HBM prefetch.
//   waves 4-7  (L0): h0(t) = GRUcell(gx(t), h0(t-1))     [6 MFMA + nonlin]
//   waves 8-11 (L1): h1(t-1) = GRUcell(h0(t-1), h1(t-2)) [12 MFMA + nonlin]
// One __syncthreads per tick.

#define Tn 512
#define Fn 128
#define Hn 64
#define An 18
// padded h row stride (halves): 72 -> 144B rows
#define HS 72

#define S_RZ (-1.4426950408889634f)
#define S_N  (-2.8853900817779268f)

typedef _Float16 half8 __attribute__((ext_vector_type(8)));
typedef _Float16 half4 __attribute__((ext_vector_type(4)));
typedef float f32x4 __attribute__((ext_vector_type(4)));

// Operand-swapped: A = weights, B = x/h fragments.
#define MFMA(w, d, c) __builtin_amdgcn_mfma_f32_16x16x32_f16((w), (d), (c), 0, 0, 0)

// Inputs pre-scaled: sigm_s(x) = 1/(1+exp2(x)) with x = -1.4427*act.
static __device__ __forceinline__ float sigm_s(float x) {
    return __builtin_amdgcn_rcpf(1.0f + __builtin_amdgcn_exp2f(x));
}
// tanh_s: x = -2.8854*act -> tanh(act) = 2/(1+exp2(x)) - 1.
static __device__ __forceinline__ float tanh_s(float x) {
    return 2.0f * __builtin_amdgcn_rcpf(1.0f + __builtin_amdgcn_exp2f(x)) - 1.0f;
}

__global__ __launch_bounds__(768) void gru_fused(
    const float* __restrict__ state,
    const float* __restrict__ Wih0, const float* __restrict__ Whh0,
    const float* __restrict__ bih0, const float* __restrict__ bhh0,
    const float* __restrict__ Wih1, const float* __restrict__ Whh1,
    const float* __restrict__ bih1, const float* __restrict__ bhh1,
    const float* __restrict__ fcw, const float* __restrict__ fcb,
    float* __restrict__ out)
{
    const int tid  = threadIdx.x;
    const int wv12 = tid >> 6;
    const int lane = tid & 63, c = lane & 15, q = lane >> 4;
    const int wv   = wv12 & 3;
    const int r0   = blockIdx.x * 16;
    const int gc   = wv * 16 + c;        // A-frag row index (channel) for W loads
    const int cb   = wv * 16 + q * 4;    // C-output channel base (4 consecutive)
    const int role = (wv12 < 4) ? 0 : (wv12 < 8 ? 1 : 2);

    __shared__ __align__(16) float    gxring[2][4][3][64][4];   // 24 KiB
    __shared__ __align__(16) _Float16 h0buf[2][16 * HS];        // 4.5 KiB
    __shared__ __align__(16) _Float16 h1buf[2][16 * HS];        // 4.5 KiB
    __shared__ float fbuf[16 * 64];                             // 4 KiB

    for (int i = tid; i < 2 * 16 * HS; i += 768) {
        (&h0buf[0][0])[i] = (_Float16)0.0f;
        (&h1buf[0][0])[i] = (_Float16)0.0f;
    }

    // Unioned weight fragments (A-operand: lane(c,q) holds W[row=ch][k=ks*32+q*8+j]):
    //  P : W[gsel*4+ks] = Wih0~ (k=128, 4 ksteps)
    //  L0: W[gsel*2+ks] = Whh0~ (k=64, 2 ksteps)
    //  L1: W[gsel*2+ks] = Wih1~ ; W[6+gsel*2+ks] = Whh1~
    // (~ = pre-scaled by S_RZ for gsel 0,1 and S_N for gsel 2)
    half8 W[12];
    f32x4 bias0, bias1, bias2, bias3;
    f32x4 xf32[8];
    f32x4 hreg = {0.f, 0.f, 0.f, 0.f};
    const float* srow = state + (size_t)(r0 + c) * (Tn * Fn);

    if (role == 0) {
#pragma unroll
        for (int gsel = 0; gsel < 3; ++gsel) {
            const float s = (gsel < 2) ? S_RZ : S_N;
            const int g = gsel * 64 + gc;
#pragma unroll
            for (int ks = 0; ks < 4; ++ks) {
                const float* p = Wih0 + g * Fn + ks * 32 + q * 8;
#pragma unroll
                for (int j = 0; j < 8; ++j) W[gsel * 4 + ks][j] = (_Float16)(s * p[j]);
            }
        }
        {
            const f32x4 bi0 = *(const f32x4*)&bih0[cb]       , bh0 = *(const f32x4*)&bhh0[cb];
            const f32x4 bi1 = *(const f32x4*)&bih0[64 + cb]  , bh1 = *(const f32x4*)&bhh0[64 + cb];
            const f32x4 bi2 = *(const f32x4*)&bih0[128 + cb];
            bias0 = (bi0 + bh0) * S_RZ;
            bias1 = (bi1 + bh1) * S_RZ;
            bias2 = bi2 * S_N;
        }
        // -------- prologue: gx(0) -> ring slot 0; preload x(1) --------
#pragma unroll
        for (int ks = 0; ks < 4; ++ks) {
            xf32[2 * ks]     = *(const f32x4*)(srow + ks * 32 + q * 8);
            xf32[2 * ks + 1] = *(const f32x4*)(srow + ks * 32 + q * 8 + 4);
        }
        half8 xf[4];
#pragma unroll
        for (int ks = 0; ks < 4; ++ks)
#pragma unroll
            for (int i = 0; i < 4; ++i) {
                xf[ks][i]     = (_Float16)xf32[2 * ks][i];
                xf[ks][4 + i] = (_Float16)xf32[2 * ks + 1][i];
            }
        f32x4 a0 = bias0, a1 = bias1, a2 = bias2;
#pragma unroll
        for (int ks = 0; ks < 4; ++ks) {
            a0 = MFMA(W[ks],     xf[ks], a0);
            a1 = MFMA(W[4 + ks], xf[ks], a1);
            a2 = MFMA(W[8 + ks], xf[ks], a2);
        }
        *(f32x4*)&gxring[0][wv][0][lane][0] = a0;
        *(f32x4*)&gxring[0][wv][1][lane][0] = a1;
        *(f32x4*)&gxring[0][wv][2][lane][0] = a2;
#pragma unroll
        for (int ks = 0; ks < 4; ++ks) {
            xf32[2 * ks]     = *(const f32x4*)(srow + Fn + ks * 32 + q * 8);
            xf32[2 * ks + 1] = *(const f32x4*)(srow + Fn + ks * 32 + q * 8 + 4);
        }
    } else if (role == 1) {
#pragma unroll
        for (int gsel = 0; gsel < 3; ++gsel) {
            const float s = (gsel < 2) ? S_RZ : S_N;
            const int g = gsel * 64 + gc;
#pragma unroll
            for (int ks = 0; ks < 2; ++ks) {
                const float* p = Whh0 + g * Hn + ks * 32 + q * 8;
#pragma unroll
                for (int j = 0; j < 8; ++j) W[gsel * 2 + ks][j] = (_Float16)(s * p[j]);
            }
        }
        bias3 = (*(const f32x4*)&bhh0[128 + cb]) * S_N;
    } else {
#pragma unroll
        for (int gsel = 0; gsel < 3; ++gsel) {
            const float s = (gsel < 2) ? S_RZ : S_N;
            const int g = gsel * 64 + gc;
#pragma unroll
            for (int ks = 0; ks < 2; ++ks) {
                const float* pa = Wih1 + g * Hn + ks * 32 + q * 8;
                const float* pb = Whh1 + g * Hn + ks * 32 + q * 8;
#pragma unroll
                for (int j = 0; j < 8; ++j) {
                    W[gsel * 2 + ks][j]     = (_Float16)(s * pa[j]);
                    W[6 + gsel * 2 + ks][j] = (_Float16)(s * pb[j]);
                }
            }
        }
        const f32x4 bi0 = *(const f32x4*)&bih1[cb]      , bh0 = *(const f32x4*)&bhh1[cb];
        const f32x4 bi1 = *(const f32x4*)&bih1[64 + cb] , bh1 = *(const f32x4*)&bhh1[64 + cb];
        bias0 = (bi0 + bh0) * S_RZ;
        bias1 = (bi1 + bh1) * S_RZ;
        bias2 = (*(const f32x4*)&bih1[128 + cb]) * S_N;
        bias3 = (*(const f32x4*)&bhh1[128 + cb]) * S_N;
    }

    const int ardr = c * HS + q * 8;      // B-frag read base (+ks*32): batch row c
    const int wofs = c * HS + cb;         // packed b64 write: batch c, 4 consecutive ch

    // Tick t: P makes gx(t+1) (t<Tn-1); L0 makes h0(t) (t<Tn); L1 makes h1(t-1) (t>=1)
    for (int t = 0; t <= Tn; ++t) {
        __syncthreads();
        const int pr = (t & 1) ^ 1, pw = t & 1;
        if (role == 0) {
            if (t < Tn - 1) {
                half8 xf[4];
#pragma unroll
                for (int ks = 0; ks < 4; ++ks)
#pragma unroll
                    for (int i = 0; i < 4; ++i) {
                        xf[ks][i]     = (_Float16)xf32[2 * ks][i];
                        xf[ks][4 + i] = (_Float16)xf32[2 * ks + 1][i];
                    }
                const int tnx = (t + 2 < Tn) ? (t + 2) : (Tn - 1);
#pragma unroll
                for (int ks = 0; ks < 4; ++ks) {
                    xf32[2 * ks]     = *(const f32x4*)(srow + (size_t)tnx * Fn + ks * 32 + q * 8);
                    xf32[2 * ks + 1] = *(const f32x4*)(srow + (size_t)tnx * Fn + ks * 32 + q * 8 + 4);
                }
                f32x4 a0 = bias0, a1 = bias1, a2 = bias2;
#pragma unroll
                for (int ks = 0; ks < 4; ++ks) {
                    a0 = MFMA(W[ks],     xf[ks], a0);
                    a1 = MFMA(W[4 + ks], xf[ks], a1);
                    a2 = MFMA(W[8 + ks], xf[ks], a2);
                }
                const int slot = (t + 1) & 1;
                *(f32x4*)&gxring[slot][wv][0][lane][0] = a0;
                *(f32x4*)&gxring[slot][wv][1][lane][0] = a1;
                *(f32x4*)&gxring[slot][wv][2][lane][0] = a2;
            }
        } else if (role == 1) {
            if (t < Tn) {
                f32x4 accr  = *(const f32x4*)&gxring[t & 1][wv][0][lane][0];
                f32x4 accz  = *(const f32x4*)&gxring[t & 1][wv][1][lane][0];
                f32x4 accxn = *(const f32x4*)&gxring[t & 1][wv][2][lane][0];
                const half8 hf0 = *(const half8*)&h0buf[pr][ardr];
                const half8 hf1 = *(const half8*)&h0buf[pr][ardr + 32];
                accr = MFMA(W[0], hf0, accr);
                accr = MFMA(W[1], hf1, accr);
                accz = MFMA(W[2], hf0, accz);
                accz = MFMA(W[3], hf1, accz);
                f32x4 acchn = MFMA(W[4], hf0, bias3);
                acchn = MFMA(W[5], hf1, acchn);
                half4 hw;
#pragma unroll
                for (int i = 0; i < 4; ++i) {
                    const float rg = sigm_s(accr[i]);
                    const float zg = sigm_s(accz[i]);
                    const float ng = tanh_s(accxn[i] + rg * acchn[i]);
                    hreg[i] = ng + zg * (hreg[i] - ng);
                    hw[i] = (_Float16)hreg[i];
                }
                *(half4*)&h0buf[pw][wofs] = hw;
            }
        } else {
            if (t >= 1) {
                const half8 xf0 = *(const half8*)&h0buf[pr][ardr];
                const half8 xf1 = *(const half8*)&h0buf[pr][ardr + 32];
                const half8 hf0 = *(const half8*)&h1buf[pw][ardr];
                const half8 hf1 = *(const half8*)&h1buf[pw][ardr + 32];
                f32x4 accr = MFMA(W[0], xf0, bias0);
                accr = MFMA(W[1], xf1, accr);
                f32x4 accz = MFMA(W[2], xf0, bias1);
                accz = MFMA(W[3], xf1, accz);
                f32x4 accxn = MFMA(W[4], xf0, bias2);
                accxn = MFMA(W[5], xf1, accxn);
                accr = MFMA(W[6], hf0, accr);
                accr = MFMA(W[7], hf1, accr);
                accz = MFMA(W[8], hf0, accz);
                accz = MFMA(W[9], hf1, accz);
                f32x4 acchn = MFMA(W[10], hf0, bias3);
                acchn = MFMA(W[11], hf1, acchn);
                half4 hw;
#pragma unroll
                for (int i = 0; i < 4; ++i) {
                    const float rg = sigm_s(accr[i]);
                    const float zg = sigm_s(accz[i]);
                    const float ng = tanh_s(accxn[i] + rg * acchn[i]);
                    hreg[i] = ng + zg * (hreg[i] - ng);
                    hw[i] = (_Float16)hreg[i];
                }
                *(half4*)&h1buf[pr][wofs] = hw;
            }
        }
    }

    // epilogue: relu(h1_final) @ fc3_w.T + fc3_b   (L1 holds (batch c, ch cb..cb+3))
    if (role == 2) {
        f32x4 fv;
#pragma unroll
        for (int i = 0; i < 4; ++i) fv[i] = fmaxf(hreg[i], 0.0f);
        *(f32x4*)&fbuf[c * 64 + cb] = fv;
    }
    __syncthreads();
    for (int idx = tid; idx < 16 * An; idx += 768) {
        const int row = idx / An, a = idx - row * An;
        float acc = fcb[a];
#pragma unroll 16
        for (int k = 0; k < Hn; ++k) acc += fbuf[row * 64 + k] * fcw[a * Hn + k];
        out[(size_t)(r0 + row) * An + a] = acc;
    }
}

extern "C" void kernel_launch(void* const* d_in, const int* in_sizes, int n_in,
                              void* d_out, int out_size, void* d_ws, size_t ws_size,
                              hipStream_t stream) {
    const float* state = (const float*)d_in[0];
    const float* Wih0  = (const float*)d_in[1];
    const float* Whh0  = (const float*)d_in[2];
    const float* bih0  = (const float*)d_in[3];
    const float* bhh0  = (const float*)d_in[4];
    const float* Wih1  = (const float*)d_in[5];
    const float* Whh1  = (const float*)d_in[6];
    const float* bih1  = (const float*)d_in[7];
    const float* bhh1  = (const float*)d_in[8];
    const float* fcw   = (const float*)d_in[9];
    const float* fcb   = (const float*)d_in[10];
    float* out = (float*)d_out;

    gru_fused<<<64, 768, 0, stream>>>(state, Wih0, Whh0, bih0, bhh0,
                                      Wih1, Whh1, bih1, bhh1, fcw, fcb, out);
}